// Round 1
// baseline (76.261 us; speedup 1.0000x reference)
//
#include <hip/hip_runtime.h>
#include <math.h>

// Four states per wave: two independent packed-f16x2 chains (P = states 0,1;
// Q = states 2,3). Base = R9-lineage verified kernel (absmax 3.9e-3) with CRX
// de-selection; this round doubles per-wave ILP to fill dependent-chain stall
// slots (theory: latency-bound serial gate chain, not issue-bound).
// Extra trims: per-lane sign masks (xor instead of NEGH+cndmask in RY_L),
// shared epilogue pre-reduction over lane bits {0,2,3,4}, float4 output store.
// permlane{16,32}_swap stays DROPPED (return-order ambiguity, two failed
// rounds in prior session). bperm stays for lane^16 / lane^32 / ring.
// Layout (verified): qubit q -> amp bit 7-((q+5)%8); amp bits 7..2 = lane
// bits 5..0, bits 1..0 = slot. Ring: src_lane = gray(lane) ^ (slot0?32:0),
// source-side reg-select predicate = SOURCE lane bit 0 (R8 errata).
// Measured: q3 -> b7 (lane bit5), q7 -> b3 (lane bit1).

typedef _Float16 h2 __attribute__((ext_vector_type(2)));

#define H2I(v) __builtin_bit_cast(int, (v))
#define I2H(v) __builtin_bit_cast(h2, (v))
#define RLF(v, i) __int_as_float(__builtin_amdgcn_readlane(__float_as_int(v), (i)))
#define RLH(v, i) I2H(__builtin_amdgcn_readlane(H2I(v), (i)))
#define BPH(a, v) I2H(__builtin_amdgcn_ds_bpermute((a), H2I(v)))
#define BPFS(a, v) __int_as_float(__builtin_amdgcn_ds_bpermute((a), __float_as_int(v)))
#define DPPH(v, ctrl) I2H(__builtin_amdgcn_update_dpp(0, H2I(v), (ctrl), 0xf, 0xf, true))
#define DPPF(v, ctrl) __uint_as_float((unsigned)__builtin_amdgcn_update_dpp( \
    0, (int)__float_as_uint(v), (ctrl), 0xf, 0xf, true))
#define NEGH(v) I2H(H2I(v) ^ 0x80008000)
#define SELH(c, a, b) I2H((c) ? H2I(a) : H2I(b))
#define FMH(a, b, c) __builtin_elementwise_fma((a), (b), (c))
#define HONE  I2H(0x3C003C00)
#define HZERO I2H(0)

#define PX1H(v)  DPPH((v), 0xB1)               // lane^1
#define PX2H(v)  DPPH((v), 0x4E)               // lane^2
#define PX4H(v)  DPPH(DPPH((v), 0x141), 0x1B)  // lane^4 (half_mirror o quad)
#define PX8H(v)  DPPH((v), 0x128)              // lane^8 (row_ror:8)
#define BP16(v)  BPH(a16, (v))
#define BP32(v)  BPH(a32, (v))
#define PX1S(v)  DPPF((v), 0xB1)
#define PX2S(v)  DPPF((v), 0x4E)
#define PX4S(v)  DPPF(DPPF((v), 0x141), 0x1B)
#define PX8S(v)  DPPF((v), 0x128)

__device__ __forceinline__ h2 mkh(float a, float b) {
    h2 r; r.x = (_Float16)a; r.y = (_Float16)b; return r;
}

__global__ __launch_bounds__(256, 4) void vqcnn_wave(
    const float* __restrict__ x,          // (B, 4, 8)
    const float* __restrict__ crx_theta,  // (10,)
    const float* __restrict__ w1,         // (10, 2)
    const float* __restrict__ b1,         // (10,)
    const float* __restrict__ w2,         // (1, 10)
    const float* __restrict__ b2,         // (1,)
    float* __restrict__ out)              // (B, 1)
{
    const int lane = threadIdx.x & 63;
    const int b0   = blockIdx.x * 16 + (threadIdx.x >> 6) * 4;  // 4 states/wave

    // angle tables: lanes 0..31 RY (idx = cyc*8+q), lanes 32..41 CRX
    float cvA, svA, cvB, svB, cvC, svC, cvD, svD;
    {
        float aA = 0.f, aB = 0.f, aC = 0.f, aD = 0.f;
        if (lane < 32) {
            aA = x[(b0 + 0) * 32 + lane]; aB = x[(b0 + 1) * 32 + lane];
            aC = x[(b0 + 2) * 32 + lane]; aD = x[(b0 + 3) * 32 + lane];
        } else if (lane < 42) {
            aA = aB = aC = aD = crx_theta[lane - 32];
        }
        __sincosf(0.5f * aA, &svA, &cvA);
        __sincosf(0.5f * aB, &svB, &cvB);
        __sincosf(0.5f * aC, &svC, &cvC);
        __sincosf(0.5f * aD, &svD, &cvD);
    }
    const h2 cvP = mkh(cvA, cvB), svP = mkh(svA, svB);
    const h2 cvQ = mkh(cvC, cvD), svQ = mkh(svC, svD);

    // bperm byte addresses (shared by both chains)
    const int a16 = (lane ^ 16) << 2;
    const int a32 = (lane ^ 32) << 2;
    const int g0  = lane ^ (lane >> 1);      // ring src lane (gray code)
    const int aE  = g0 << 2;                 // even dest slots (s0=0)
    const int aO  = (g0 ^ 32) << 2;          // odd dest slots  (s0=1)
    const bool l0r = (lane & 1) != 0;        // ring source-select predicate

    // per-lane RY sign masks: bit set -> +s (mask 0), bit clear -> -s (flip)
    const int sg1  = (lane &  1) ? 0 : 0x80008000;
    const int sg2  = (lane &  2) ? 0 : 0x80008000;
    const int sg4  = (lane &  4) ? 0 : 0x80008000;
    const int sg8  = (lane &  8) ? 0 : 0x80008000;
    const int sg16 = (lane & 16) ? 0 : 0x80008000;
    const int sg32 = (lane & 32) ? 0 : 0x80008000;

    // ---- cycle 0: product state in f32, then pack ----
#define INIT0(V0, V1, V2, V3, CVa, SVa, CVb, SVb) {                          \
    float _LA = (lane & 32) ? RLF(SVa, 3) : RLF(CVa, 3);  /* q3 -> b7 */     \
    float _LB = (lane & 32) ? RLF(SVb, 3) : RLF(CVb, 3);                     \
    _LA *= (lane & 16) ? RLF(SVa, 4) : RLF(CVa, 4);       /* q4 -> b6 */     \
    _LB *= (lane & 16) ? RLF(SVb, 4) : RLF(CVb, 4);                          \
    _LA *= (lane &  8) ? RLF(SVa, 5) : RLF(CVa, 5);       /* q5 -> b5 */     \
    _LB *= (lane &  8) ? RLF(SVb, 5) : RLF(CVb, 5);                          \
    _LA *= (lane &  4) ? RLF(SVa, 6) : RLF(CVa, 6);       /* q6 -> b4 */     \
    _LB *= (lane &  4) ? RLF(SVb, 6) : RLF(CVb, 6);                          \
    _LA *= (lane &  2) ? RLF(SVa, 7) : RLF(CVa, 7);       /* q7 -> b3 */     \
    _LB *= (lane &  2) ? RLF(SVb, 7) : RLF(CVb, 7);                          \
    _LA *= (lane &  1) ? RLF(SVa, 0) : RLF(CVa, 0);       /* q0 -> b2 */     \
    _LB *= (lane &  1) ? RLF(SVb, 0) : RLF(CVb, 0);                          \
    const float _c1a = RLF(CVa, 1), _s1a = RLF(SVa, 1);   /* q1 -> b1 */     \
    const float _c2a = RLF(CVa, 2), _s2a = RLF(SVa, 2);   /* q2 -> b0 */     \
    const float _c1b = RLF(CVb, 1), _s1b = RLF(SVb, 1);                      \
    const float _c2b = RLF(CVb, 2), _s2b = RLF(SVb, 2);                      \
    V0 = mkh(_LA * _c1a * _c2a, _LB * _c1b * _c2b);                          \
    V1 = mkh(_LA * _c1a * _s2a, _LB * _c1b * _s2b);                          \
    V2 = mkh(_LA * _s1a * _c2a, _LB * _s1b * _c2b);                          \
    V3 = mkh(_LA * _s1a * _s2a, _LB * _s1b * _s2b); }

    h2 vP0, vP1, vP2, vP3, vQ0, vQ1, vQ2, vQ3;
    INIT0(vP0, vP1, vP2, vP3, cvA, svA, cvB, svB)
    INIT0(vQ0, vQ1, vQ2, vQ3, cvC, svC, cvD, svD)

    // composed CNOT ring: source-side merged gather, predicate = lane&1
#define RING1(V0, V1, V2, V3) {                                              \
    const h2 _z0 = SELH(l0r, V2, V0);                                        \
    const h2 _z1 = SELH(l0r, V3, V1);                                        \
    const h2 _z2 = SELH(l0r, V1, V3);                                        \
    const h2 _z3 = SELH(l0r, V0, V2);                                        \
    V0 = BPH(aE, _z0); V1 = BPH(aO, _z1);                                    \
    V2 = BPH(aE, _z2); V3 = BPH(aO, _z3); }

    RING1(vP0, vP1, vP2, vP3)
    RING1(vQ0, vQ1, vQ2, vQ3)

    // RY lane-exchange gate: new = c*v + (sign-masked s) * partner
#define RY_L1(V0, V1, V2, V3, CT, ST, ia, sgm, EX) {                         \
    const h2 _c = RLH(CT, (ia)), _s = RLH(ST, (ia));                         \
    const h2 _sn = I2H(H2I(_s) ^ (sgm));                                     \
    const h2 _p0 = EX(V0), _p1 = EX(V1);                                     \
    const h2 _p2 = EX(V2), _p3 = EX(V3);                                     \
    V0 = FMH(_sn, _p0, _c * V0); V1 = FMH(_sn, _p1, _c * V1);                \
    V2 = FMH(_sn, _p2, _c * V2); V3 = FMH(_sn, _p3, _c * V3); }

    // RY on slot bit1 (q1): pairs (0,2),(1,3)
#define RY_S1a(V0, V1, V2, V3, CT, ST, ia) {                                 \
    const h2 _c = RLH(CT, (ia)), _s = RLH(ST, (ia)), _ns = NEGH(_s);         \
    const h2 _n0 = FMH(_ns, V2, _c * V0), _n2 = FMH(_s, V0, _c * V2);        \
    const h2 _n1 = FMH(_ns, V3, _c * V1), _n3 = FMH(_s, V1, _c * V3);        \
    V0 = _n0; V1 = _n1; V2 = _n2; V3 = _n3; }

    // RY on slot bit0 (q2): pairs (0,1),(2,3)
#define RY_S0a(V0, V1, V2, V3, CT, ST, ia) {                                 \
    const h2 _c = RLH(CT, (ia)), _s = RLH(ST, (ia)), _ns = NEGH(_s);         \
    const h2 _n0 = FMH(_ns, V1, _c * V0), _n1 = FMH(_s, V0, _c * V1);        \
    const h2 _n2 = FMH(_ns, V3, _c * V2), _n3 = FMH(_s, V2, _c * V3);        \
    V0 = _n0; V1 = _n1; V2 = _n2; V3 = _n3; }

    // ---- cycles 1..3: 8 RY + ring (real arithmetic, f16 packed, 2 chains) ----
    #pragma unroll
    for (int cyc = 1; cyc < 4; ++cyc) {
        const int base = cyc * 8;
        RY_L1(vP0, vP1, vP2, vP3, cvP, svP, base + 0, sg1, PX1H)   // q0 -> b2
        RY_L1(vQ0, vQ1, vQ2, vQ3, cvQ, svQ, base + 0, sg1, PX1H)
        RY_S1a(vP0, vP1, vP2, vP3, cvP, svP, base + 1)             // q1 -> b1
        RY_S1a(vQ0, vQ1, vQ2, vQ3, cvQ, svQ, base + 1)
        RY_S0a(vP0, vP1, vP2, vP3, cvP, svP, base + 2)             // q2 -> b0
        RY_S0a(vQ0, vQ1, vQ2, vQ3, cvQ, svQ, base + 2)
        RY_L1(vP0, vP1, vP2, vP3, cvP, svP, base + 3, sg32, BP32)  // q3 -> b7
        RY_L1(vQ0, vQ1, vQ2, vQ3, cvQ, svQ, base + 3, sg32, BP32)
        RY_L1(vP0, vP1, vP2, vP3, cvP, svP, base + 4, sg16, BP16)  // q4 -> b6
        RY_L1(vQ0, vQ1, vQ2, vQ3, cvQ, svQ, base + 4, sg16, BP16)
        RY_L1(vP0, vP1, vP2, vP3, cvP, svP, base + 5, sg8, PX8H)   // q5 -> b5
        RY_L1(vQ0, vQ1, vQ2, vQ3, cvQ, svQ, base + 5, sg8, PX8H)
        RY_L1(vP0, vP1, vP2, vP3, cvP, svP, base + 6, sg4, PX4H)   // q6 -> b4
        RY_L1(vQ0, vQ1, vQ2, vQ3, cvQ, svQ, base + 6, sg4, PX4H)
        RY_L1(vP0, vP1, vP2, vP3, cvP, svP, base + 7, sg2, PX2H)   // q7 -> b3
        RY_L1(vQ0, vQ1, vQ2, vQ3, cvQ, svQ, base + 7, sg2, PX2H)
        RING1(vP0, vP1, vP2, vP3)
        RING1(vQ0, vQ1, vQ2, vQ3)
    }

    // ---- Phase 2: 10 CRX gates (complex, f16 packed, de-selected coeffs) ----
    h2 rP0 = vP0, rP1 = vP1, rP2 = vP2, rP3 = vP3;
    h2 iP0 = HZERO, iP1 = HZERO, iP2 = HZERO, iP3 = HZERO;
    h2 rQ0 = vQ0, rQ1 = vQ1, rQ2 = vQ2, rQ3 = vQ3;
    h2 iQ0 = HZERO, iQ1 = HZERO, iQ2 = HZERO, iQ3 = HZERO;

    // CRX with exchange EX; ctrl folded into coefficients (c'=ct?c:1, s'=ct?s:0)
#define CRX_Ga(R0, R1, R2, R3, I0, I1, I2, I3, CT, ST, gi, cmask, EX) {      \
    const bool _ct = (lane & (cmask)) != 0;                                  \
    const h2 _c = SELH(_ct, RLH(CT, 32 + (gi)), HONE);                       \
    const h2 _s = SELH(_ct, RLH(ST, 32 + (gi)), HZERO);                      \
    const h2 _ns = NEGH(_s);                                                 \
    const h2 _pr0 = EX(R0), _pi0 = EX(I0);                                   \
    const h2 _pr1 = EX(R1), _pi1 = EX(I1);                                   \
    const h2 _pr2 = EX(R2), _pi2 = EX(I2);                                   \
    const h2 _pr3 = EX(R3), _pi3 = EX(I3);                                   \
    R0 = FMH(_s, _pi0, _c * R0); I0 = FMH(_ns, _pr0, _c * I0);               \
    R1 = FMH(_s, _pi1, _c * R1); I1 = FMH(_ns, _pr1, _c * I1);               \
    R2 = FMH(_s, _pi2, _c * R2); I2 = FMH(_ns, _pr2, _c * I2);               \
    R3 = FMH(_s, _pi3, _c * R3); I3 = FMH(_ns, _pr3, _c * I3); }

    // gates 0 & 8: ctrl b2 (lane&1), target slot bit1: pairs (0,2),(1,3)
#define CRX_SLOT1a(R0, R1, R2, R3, I0, I1, I2, I3, CT, ST, gi) {             \
    const bool _ct = (lane & 1) != 0;                                        \
    const h2 _c = SELH(_ct, RLH(CT, 32 + (gi)), HONE);                       \
    const h2 _s = SELH(_ct, RLH(ST, 32 + (gi)), HZERO);                      \
    const h2 _ns = NEGH(_s);                                                 \
    const h2 _nr0 = FMH(_s, I2, _c * R0), _ni0 = FMH(_ns, R2, _c * I0);      \
    const h2 _nr2 = FMH(_s, I0, _c * R2), _ni2 = FMH(_ns, R0, _c * I2);      \
    const h2 _nr1 = FMH(_s, I3, _c * R1), _ni1 = FMH(_ns, R3, _c * I1);      \
    const h2 _nr3 = FMH(_s, I1, _c * R3), _ni3 = FMH(_ns, R1, _c * I3);      \
    R0 = _nr0; I0 = _ni0; R1 = _nr1; I1 = _ni1;                              \
    R2 = _nr2; I2 = _ni2; R3 = _nr3; I3 = _ni3; }

    // gates 1 & 9: ctrl slot bit1 (regs 2,3 always ctrl'd), target slot bit0
#define CRX_SLOT0a(R2, R3, I2, I3, CT, ST, gi) {                             \
    const h2 _c = RLH(CT, 32 + (gi)), _s = RLH(ST, 32 + (gi));               \
    const h2 _ns = NEGH(_s);                                                 \
    const h2 _nr2 = FMH(_s, I3, _c * R2), _ni2 = FMH(_ns, R3, _c * I2);      \
    const h2 _nr3 = FMH(_s, I2, _c * R3), _ni3 = FMH(_ns, R2, _c * I3);      \
    R2 = _nr2; I2 = _ni2; R3 = _nr3; I3 = _ni3; }

    // gate 2: c=q2(b0: regs 1,3 always ctrl'd), t=q3(b7: lane^32)
#define CRX_I2(R1, R3, I1, I3, CT, ST) {                                     \
    const h2 _c = RLH(CT, 34), _s = RLH(ST, 34), _ns = NEGH(_s);             \
    const h2 _pr1 = BP32(R1), _pi1 = BP32(I1);                               \
    const h2 _pr3 = BP32(R3), _pi3 = BP32(I3);                               \
    R1 = FMH(_s, _pi1, _c * R1); I1 = FMH(_ns, _pr1, _c * I1);               \
    R3 = FMH(_s, _pi3, _c * R3); I3 = FMH(_ns, _pr3, _c * I3); }

    CRX_SLOT1a(rP0, rP1, rP2, rP3, iP0, iP1, iP2, iP3, cvP, svP, 0)
    CRX_SLOT1a(rQ0, rQ1, rQ2, rQ3, iQ0, iQ1, iQ2, iQ3, cvQ, svQ, 0)
    CRX_SLOT0a(rP2, rP3, iP2, iP3, cvP, svP, 1)
    CRX_SLOT0a(rQ2, rQ3, iQ2, iQ3, cvQ, svQ, 1)
    CRX_I2(rP1, rP3, iP1, iP3, cvP, svP)
    CRX_I2(rQ1, rQ3, iQ1, iQ3, cvQ, svQ)
    CRX_Ga(rP0, rP1, rP2, rP3, iP0, iP1, iP2, iP3, cvP, svP, 3, 32, BP16)
    CRX_Ga(rQ0, rQ1, rQ2, rQ3, iQ0, iQ1, iQ2, iQ3, cvQ, svQ, 3, 32, BP16)
    CRX_Ga(rP0, rP1, rP2, rP3, iP0, iP1, iP2, iP3, cvP, svP, 4, 16, PX8H)
    CRX_Ga(rQ0, rQ1, rQ2, rQ3, iQ0, iQ1, iQ2, iQ3, cvQ, svQ, 4, 16, PX8H)
    CRX_Ga(rP0, rP1, rP2, rP3, iP0, iP1, iP2, iP3, cvP, svP, 5, 8, PX4H)
    CRX_Ga(rQ0, rQ1, rQ2, rQ3, iQ0, iQ1, iQ2, iQ3, cvQ, svQ, 5, 8, PX4H)
    CRX_Ga(rP0, rP1, rP2, rP3, iP0, iP1, iP2, iP3, cvP, svP, 6, 4, PX2H)
    CRX_Ga(rQ0, rQ1, rQ2, rQ3, iQ0, iQ1, iQ2, iQ3, cvQ, svQ, 6, 4, PX2H)
    CRX_Ga(rP0, rP1, rP2, rP3, iP0, iP1, iP2, iP3, cvP, svP, 7, 2, PX1H)
    CRX_Ga(rQ0, rQ1, rQ2, rQ3, iQ0, iQ1, iQ2, iQ3, cvQ, svQ, 7, 2, PX1H)
    CRX_SLOT1a(rP0, rP1, rP2, rP3, iP0, iP1, iP2, iP3, cvP, svP, 8)
    CRX_SLOT1a(rQ0, rQ1, rQ2, rQ3, iQ0, iQ1, iQ2, iQ3, cvQ, svQ, 8)
    CRX_SLOT0a(rP2, rP3, iP2, iP3, cvP, svP, 9)
    CRX_SLOT0a(rQ2, rQ3, iQ2, iQ3, cvQ, svQ, 9)

    // ---- probs (f16) -> f32 epilogue ----
    const h2 pP0 = FMH(rP0, rP0, iP0 * iP0);
    const h2 pP1 = FMH(rP1, rP1, iP1 * iP1);
    const h2 pP2 = FMH(rP2, rP2, iP2 * iP2);
    const h2 pP3 = FMH(rP3, rP3, iP3 * iP3);
    const h2 apP = (pP0 + pP1) + (pP2 + pP3);
    const h2 pQ0 = FMH(rQ0, rQ0, iQ0 * iQ0);
    const h2 pQ1 = FMH(rQ1, rQ1, iQ1 * iQ1);
    const h2 pQ2 = FMH(rQ2, rQ2, iQ2 * iQ2);
    const h2 pQ3 = FMH(rQ3, rQ3, iQ3 * iQ3);
    const h2 apQ = (pQ0 + pQ1) + (pQ2 + pQ3);
    float aAf = (float)apP.x, aBf = (float)apP.y;
    float aCf = (float)apQ.x, aDf = (float)apQ.y;

    // shared pre-reduction over lane bits {0,2,3,4} (sign-independent for
    // both z3 (bit5) and z7 (bit1)); then sign + finish over bits {5,1}.
#define RED4(v) { v += PX1S(v); v += PX4S(v); v += PX8S(v); v += BPFS(a16, v); }
    RED4(aAf) RED4(aBf) RED4(aCf) RED4(aDf)

#define ZPAIR(af, Z3, Z7)                                                    \
    float Z3 = (lane & 32) ? -(af) : (af);   /* q3 -> b7 (lane bit5) */      \
    Z3 += BPFS(a32, Z3); Z3 += PX2S(Z3);                                     \
    float Z7 = (lane & 2) ? -(af) : (af);    /* q7 -> b3 (lane bit1) */      \
    Z7 += PX2S(Z7); Z7 += BPFS(a32, Z7);

    ZPAIR(aAf, z3A, z7A)
    ZPAIR(aBf, z3B, z7B)
    ZPAIR(aCf, z3C, z7C)
    ZPAIR(aDf, z3D, z7D)

    // ---- MLP: lane u (<10) computes hidden unit u for all four states ----
    float wa = 0.f, wb = 0.f, bb = 0.f, wc = 0.f;
    if (lane < 10) {
        wa = w1[2 * lane];
        wb = w1[2 * lane + 1];
        bb = b1[lane];
        wc = w2[lane];
    }
    const float zA = fmaf(wa, z3A, fmaf(wb, z7A, bb));
    const float zB = fmaf(wa, z3B, fmaf(wb, z7B, bb));
    const float zC = fmaf(wa, z3C, fmaf(wb, z7C, bb));
    const float zD = fmaf(wa, z3D, fmaf(wb, z7D, bb));
    const float eA = __expf(2.0f * zA), eB = __expf(2.0f * zB);
    const float eC = __expf(2.0f * zC), eD = __expf(2.0f * zD);
    const float hA = 1.0f - 2.0f * __builtin_amdgcn_rcpf(eA + 1.0f);
    const float hB = 1.0f - 2.0f * __builtin_amdgcn_rcpf(eB + 1.0f);
    const float hC = 1.0f - 2.0f * __builtin_amdgcn_rcpf(eC + 1.0f);
    const float hD = 1.0f - 2.0f * __builtin_amdgcn_rcpf(eD + 1.0f);
    float accA = wc * hA, accB = wc * hB;    // lanes >=10 contribute 0
    float accC = wc * hC, accD = wc * hD;
    accA += PX1S(accA); accB += PX1S(accB); accC += PX1S(accC); accD += PX1S(accD);
    accA += PX2S(accA); accB += PX2S(accB); accC += PX2S(accC); accD += PX2S(accD);
    accA += PX4S(accA); accB += PX4S(accB); accC += PX4S(accC); accD += PX4S(accD);
    accA += PX8S(accA); accB += PX8S(accB); accC += PX8S(accC); accD += PX8S(accD);
    if (lane == 0) {
        const float bias = b2[0];
        float4 o;
        o.x = __builtin_amdgcn_rcpf(1.0f + __expf(-(accA + bias)));
        o.y = __builtin_amdgcn_rcpf(1.0f + __expf(-(accB + bias)));
        o.z = __builtin_amdgcn_rcpf(1.0f + __expf(-(accC + bias)));
        o.w = __builtin_amdgcn_rcpf(1.0f + __expf(-(accD + bias)));
        *reinterpret_cast<float4*>(out + b0) = o;
    }
}

extern "C" void kernel_launch(void* const* d_in, const int* in_sizes, int n_in,
                              void* d_out, int out_size, void* d_ws, size_t ws_size,
                              hipStream_t stream) {
    const float* x         = (const float*)d_in[0];
    const float* crx_theta = (const float*)d_in[1];
    const float* w1        = (const float*)d_in[2];
    const float* b1        = (const float*)d_in[3];
    const float* w2        = (const float*)d_in[4];
    const float* b2        = (const float*)d_in[5];
    float* out = (float*)d_out;

    const int B = in_sizes[0] / 32;  // x is (B, 4, 8)
    vqcnn_wave<<<B / 16, 256, 0, stream>>>(x, crx_theta, w1, b1, w2, b2, out);
}

// Round 3
// 74.966 us; speedup vs baseline: 1.0173x; 1.0173x over previous
//
#include <hip/hip_runtime.h>
#include <math.h>

// Four states per wave, two independent packed-f16x2 chains (P, Q).
// R3 = R1's verified data movement (ds_bpermute for lane^16/lane^32 + ring;
// absmax 3.9e-3) + CRX pruning only:
//  - gates 7,8,9 PRUNED (exact): gate7 (c=q7,t=q0) commutes with Z_q7 so
//    <Z_q7> preserved and acts only on {q0,q7} so <Z_q3> marginal unchanged;
//    gates 8,9 act only on qubits {0,1,2}; measured qubits are (3,7).
//  - gate 0 specialized for imag==0 input (state is real after RY/ring phase).
// permlane{16,32}_swap is PERMANENTLY BANNED for this kernel: three failed
// attempts (two prior-session + R2's runtime-calibrated form, absmax 0.248).
// HW behavior does not match any modeled return convention. bperm only.
// Layout (verified): qubit q -> amp bit 7-((q+5)%8); amp bits 7..2 = lane
// bits 5..0, bits 1..0 = slot. Ring: src_lane = gray(lane) ^ (slot0?32:0),
// source-side reg-select predicate = SOURCE lane bit 0 (R8 errata).
// Measured: q3 -> b7 (lane bit5), q7 -> b3 (lane bit1).

typedef _Float16 h2 __attribute__((ext_vector_type(2)));

#define H2I(v) __builtin_bit_cast(int, (v))
#define I2H(v) __builtin_bit_cast(h2, (v))
#define RLF(v, i) __int_as_float(__builtin_amdgcn_readlane(__float_as_int(v), (i)))
#define RLH(v, i) I2H(__builtin_amdgcn_readlane(H2I(v), (i)))
#define BPH(a, v) I2H(__builtin_amdgcn_ds_bpermute((a), H2I(v)))
#define BPFS(a, v) __int_as_float(__builtin_amdgcn_ds_bpermute((a), __float_as_int(v)))
#define DPPH(v, ctrl) I2H(__builtin_amdgcn_update_dpp(0, H2I(v), (ctrl), 0xf, 0xf, true))
#define DPPF(v, ctrl) __uint_as_float((unsigned)__builtin_amdgcn_update_dpp( \
    0, (int)__float_as_uint(v), (ctrl), 0xf, 0xf, true))
#define NEGH(v) I2H(H2I(v) ^ 0x80008000)
#define SELH(c, a, b) I2H((c) ? H2I(a) : H2I(b))
#define FMH(a, b, c) __builtin_elementwise_fma((a), (b), (c))
#define HONE  I2H(0x3C003C00)
#define HZERO I2H(0)

#define PX1H(v)  DPPH((v), 0xB1)               // lane^1
#define PX2H(v)  DPPH((v), 0x4E)               // lane^2
#define PX4H(v)  DPPH(DPPH((v), 0x141), 0x1B)  // lane^4 (half_mirror o quad)
#define PX8H(v)  DPPH((v), 0x128)              // lane^8 (row_ror:8)
#define BP16(v)  BPH(a16, (v))
#define BP32(v)  BPH(a32, (v))
#define PX1S(v)  DPPF((v), 0xB1)
#define PX2S(v)  DPPF((v), 0x4E)
#define PX4S(v)  DPPF(DPPF((v), 0x141), 0x1B)
#define PX8S(v)  DPPF((v), 0x128)

__device__ __forceinline__ h2 mkh(float a, float b) {
    h2 r; r.x = (_Float16)a; r.y = (_Float16)b; return r;
}

__global__ __launch_bounds__(256, 4) void vqcnn_wave(
    const float* __restrict__ x,          // (B, 4, 8)
    const float* __restrict__ crx_theta,  // (10,)
    const float* __restrict__ w1,         // (10, 2)
    const float* __restrict__ b1,         // (10,)
    const float* __restrict__ w2,         // (1, 10)
    const float* __restrict__ b2,         // (1,)
    float* __restrict__ out)              // (B, 1)
{
    const int lane = threadIdx.x & 63;
    const int b0   = blockIdx.x * 16 + (threadIdx.x >> 6) * 4;  // 4 states/wave

    // angle tables: lanes 0..31 RY (idx = cyc*8+q), lanes 32..41 CRX
    float cvA, svA, cvB, svB, cvC, svC, cvD, svD;
    {
        float aA = 0.f, aB = 0.f, aC = 0.f, aD = 0.f;
        if (lane < 32) {
            aA = x[(b0 + 0) * 32 + lane]; aB = x[(b0 + 1) * 32 + lane];
            aC = x[(b0 + 2) * 32 + lane]; aD = x[(b0 + 3) * 32 + lane];
        } else if (lane < 42) {
            aA = aB = aC = aD = crx_theta[lane - 32];
        }
        __sincosf(0.5f * aA, &svA, &cvA);
        __sincosf(0.5f * aB, &svB, &cvB);
        __sincosf(0.5f * aC, &svC, &cvC);
        __sincosf(0.5f * aD, &svD, &cvD);
    }
    const h2 cvP = mkh(cvA, cvB), svP = mkh(svA, svB);
    const h2 cvQ = mkh(cvC, cvD), svQ = mkh(svC, svD);

    // bperm byte addresses (shared by both chains)
    const int a16 = (lane ^ 16) << 2;
    const int a32 = (lane ^ 32) << 2;
    const int g0  = lane ^ (lane >> 1);      // ring src lane (gray code)
    const int aE  = g0 << 2;                 // even dest slots (s0=0)
    const int aO  = (g0 ^ 32) << 2;          // odd dest slots  (s0=1)
    const bool l0r = (lane & 1) != 0;        // ring source-select predicate

    // per-lane RY sign masks: bit set -> +s (mask 0), bit clear -> -s (flip)
    const int sg1  = (lane &  1) ? 0 : 0x80008000;
    const int sg2  = (lane &  2) ? 0 : 0x80008000;
    const int sg4  = (lane &  4) ? 0 : 0x80008000;
    const int sg8  = (lane &  8) ? 0 : 0x80008000;
    const int sg16 = (lane & 16) ? 0 : 0x80008000;
    const int sg32 = (lane & 32) ? 0 : 0x80008000;

    // ---- cycle 0: product state in f32, then pack ----
#define INIT0(V0, V1, V2, V3, CVa, SVa, CVb, SVb) {                          \
    float _LA = (lane & 32) ? RLF(SVa, 3) : RLF(CVa, 3);  /* q3 -> b7 */     \
    float _LB = (lane & 32) ? RLF(SVb, 3) : RLF(CVb, 3);                     \
    _LA *= (lane & 16) ? RLF(SVa, 4) : RLF(CVa, 4);       /* q4 -> b6 */     \
    _LB *= (lane & 16) ? RLF(SVb, 4) : RLF(CVb, 4);                          \
    _LA *= (lane &  8) ? RLF(SVa, 5) : RLF(CVa, 5);       /* q5 -> b5 */     \
    _LB *= (lane &  8) ? RLF(SVb, 5) : RLF(CVb, 5);                          \
    _LA *= (lane &  4) ? RLF(SVa, 6) : RLF(CVa, 6);       /* q6 -> b4 */     \
    _LB *= (lane &  4) ? RLF(SVb, 6) : RLF(CVb, 6);                          \
    _LA *= (lane &  2) ? RLF(SVa, 7) : RLF(CVa, 7);       /* q7 -> b3 */     \
    _LB *= (lane &  2) ? RLF(SVb, 7) : RLF(CVb, 7);                          \
    _LA *= (lane &  1) ? RLF(SVa, 0) : RLF(CVa, 0);       /* q0 -> b2 */     \
    _LB *= (lane &  1) ? RLF(SVb, 0) : RLF(CVb, 0);                          \
    const float _c1a = RLF(CVa, 1), _s1a = RLF(SVa, 1);   /* q1 -> b1 */     \
    const float _c2a = RLF(CVa, 2), _s2a = RLF(SVa, 2);   /* q2 -> b0 */     \
    const float _c1b = RLF(CVb, 1), _s1b = RLF(SVb, 1);                      \
    const float _c2b = RLF(CVb, 2), _s2b = RLF(SVb, 2);                      \
    V0 = mkh(_LA * _c1a * _c2a, _LB * _c1b * _c2b);                          \
    V1 = mkh(_LA * _c1a * _s2a, _LB * _c1b * _s2b);                          \
    V2 = mkh(_LA * _s1a * _c2a, _LB * _s1b * _c2b);                          \
    V3 = mkh(_LA * _s1a * _s2a, _LB * _s1b * _s2b); }

    h2 vP0, vP1, vP2, vP3, vQ0, vQ1, vQ2, vQ3;
    INIT0(vP0, vP1, vP2, vP3, cvA, svA, cvB, svB)
    INIT0(vQ0, vQ1, vQ2, vQ3, cvC, svC, cvD, svD)

    // composed CNOT ring: source-side merged gather, predicate = lane&1
#define RING1(V0, V1, V2, V3) {                                              \
    const h2 _z0 = SELH(l0r, V2, V0);                                        \
    const h2 _z1 = SELH(l0r, V3, V1);                                        \
    const h2 _z2 = SELH(l0r, V1, V3);                                        \
    const h2 _z3 = SELH(l0r, V0, V2);                                        \
    V0 = BPH(aE, _z0); V1 = BPH(aO, _z1);                                    \
    V2 = BPH(aE, _z2); V3 = BPH(aO, _z3); }

    RING1(vP0, vP1, vP2, vP3)
    RING1(vQ0, vQ1, vQ2, vQ3)

    // RY lane-exchange gate: new = c*v + (sign-masked s) * partner
#define RY_L1(V0, V1, V2, V3, CT, ST, ia, sgm, EX) {                         \
    const h2 _c = RLH(CT, (ia)), _s = RLH(ST, (ia));                         \
    const h2 _sn = I2H(H2I(_s) ^ (sgm));                                     \
    const h2 _p0 = EX(V0), _p1 = EX(V1);                                     \
    const h2 _p2 = EX(V2), _p3 = EX(V3);                                     \
    V0 = FMH(_sn, _p0, _c * V0); V1 = FMH(_sn, _p1, _c * V1);                \
    V2 = FMH(_sn, _p2, _c * V2); V3 = FMH(_sn, _p3, _c * V3); }

    // RY on slot bit1 (q1): pairs (0,2),(1,3)
#define RY_S1a(V0, V1, V2, V3, CT, ST, ia) {                                 \
    const h2 _c = RLH(CT, (ia)), _s = RLH(ST, (ia)), _ns = NEGH(_s);         \
    const h2 _n0 = FMH(_ns, V2, _c * V0), _n2 = FMH(_s, V0, _c * V2);        \
    const h2 _n1 = FMH(_ns, V3, _c * V1), _n3 = FMH(_s, V1, _c * V3);        \
    V0 = _n0; V1 = _n1; V2 = _n2; V3 = _n3; }

    // RY on slot bit0 (q2): pairs (0,1),(2,3)
#define RY_S0a(V0, V1, V2, V3, CT, ST, ia) {                                 \
    const h2 _c = RLH(CT, (ia)), _s = RLH(ST, (ia)), _ns = NEGH(_s);         \
    const h2 _n0 = FMH(_ns, V1, _c * V0), _n1 = FMH(_s, V0, _c * V1);        \
    const h2 _n2 = FMH(_ns, V3, _c * V2), _n3 = FMH(_s, V2, _c * V3);        \
    V0 = _n0; V1 = _n1; V2 = _n2; V3 = _n3; }

    // ---- cycles 1..3: 8 RY + ring (real arithmetic, f16 packed, 2 chains) ----
    #pragma unroll
    for (int cyc = 1; cyc < 4; ++cyc) {
        const int base = cyc * 8;
        RY_L1(vP0, vP1, vP2, vP3, cvP, svP, base + 0, sg1, PX1H)   // q0 -> b2
        RY_L1(vQ0, vQ1, vQ2, vQ3, cvQ, svQ, base + 0, sg1, PX1H)
        RY_S1a(vP0, vP1, vP2, vP3, cvP, svP, base + 1)             // q1 -> b1
        RY_S1a(vQ0, vQ1, vQ2, vQ3, cvQ, svQ, base + 1)
        RY_S0a(vP0, vP1, vP2, vP3, cvP, svP, base + 2)             // q2 -> b0
        RY_S0a(vQ0, vQ1, vQ2, vQ3, cvQ, svQ, base + 2)
        RY_L1(vP0, vP1, vP2, vP3, cvP, svP, base + 3, sg32, BP32)  // q3 -> b7
        RY_L1(vQ0, vQ1, vQ2, vQ3, cvQ, svQ, base + 3, sg32, BP32)
        RY_L1(vP0, vP1, vP2, vP3, cvP, svP, base + 4, sg16, BP16)  // q4 -> b6
        RY_L1(vQ0, vQ1, vQ2, vQ3, cvQ, svQ, base + 4, sg16, BP16)
        RY_L1(vP0, vP1, vP2, vP3, cvP, svP, base + 5, sg8, PX8H)   // q5 -> b5
        RY_L1(vQ0, vQ1, vQ2, vQ3, cvQ, svQ, base + 5, sg8, PX8H)
        RY_L1(vP0, vP1, vP2, vP3, cvP, svP, base + 6, sg4, PX4H)   // q6 -> b4
        RY_L1(vQ0, vQ1, vQ2, vQ3, cvQ, svQ, base + 6, sg4, PX4H)
        RY_L1(vP0, vP1, vP2, vP3, cvP, svP, base + 7, sg2, PX2H)   // q7 -> b3
        RY_L1(vQ0, vQ1, vQ2, vQ3, cvQ, svQ, base + 7, sg2, PX2H)
        RING1(vP0, vP1, vP2, vP3)
        RING1(vQ0, vQ1, vQ2, vQ3)
    }

    // ---- Phase 2: CRX gates 0..6 only (7,8,9 pruned — exact, see header) ----
    h2 rP0 = vP0, rP1 = vP1, rP2 = vP2, rP3 = vP3;
    h2 iP0, iP1, iP2, iP3;
    h2 rQ0 = vQ0, rQ1 = vQ1, rQ2 = vQ2, rQ3 = vQ3;
    h2 iQ0, iQ1, iQ2, iQ3;

    // gate 0 specialized for imag==0 input: i' = -s'*rPartner, r' = c'*r
    // (c'=ct?c:1, s'=ct?s:0; partner pairs (0,2),(1,3); all I reads of R
    // happen before R is scaled)
#define CRX_SLOT1_FIRST(R0, R1, R2, R3, I0, I1, I2, I3, CT, ST) {            \
    const bool _ct = (lane & 1) != 0;                                        \
    const h2 _c = SELH(_ct, RLH(CT, 32), HONE);                              \
    const h2 _s = SELH(_ct, RLH(ST, 32), HZERO);                             \
    const h2 _ns = NEGH(_s);                                                 \
    I0 = _ns * R2; I2 = _ns * R0; I1 = _ns * R3; I3 = _ns * R1;              \
    R0 = _c * R0; R2 = _c * R2; R1 = _c * R1; R3 = _c * R3; }

    // CRX with exchange EX; ctrl folded into coefficients (c'=ct?c:1, s'=ct?s:0)
#define CRX_Ga(R0, R1, R2, R3, I0, I1, I2, I3, CT, ST, gi, cmask, EX) {      \
    const bool _ct = (lane & (cmask)) != 0;                                  \
    const h2 _c = SELH(_ct, RLH(CT, 32 + (gi)), HONE);                       \
    const h2 _s = SELH(_ct, RLH(ST, 32 + (gi)), HZERO);                      \
    const h2 _ns = NEGH(_s);                                                 \
    const h2 _pr0 = EX(R0), _pi0 = EX(I0);                                   \
    const h2 _pr1 = EX(R1), _pi1 = EX(I1);                                   \
    const h2 _pr2 = EX(R2), _pi2 = EX(I2);                                   \
    const h2 _pr3 = EX(R3), _pi3 = EX(I3);                                   \
    R0 = FMH(_s, _pi0, _c * R0); I0 = FMH(_ns, _pr0, _c * I0);               \
    R1 = FMH(_s, _pi1, _c * R1); I1 = FMH(_ns, _pr1, _c * I1);               \
    R2 = FMH(_s, _pi2, _c * R2); I2 = FMH(_ns, _pr2, _c * I2);               \
    R3 = FMH(_s, _pi3, _c * R3); I3 = FMH(_ns, _pr3, _c * I3); }

    // gate 1: ctrl slot bit1 (regs 2,3 always ctrl'd), target slot bit0
#define CRX_SLOT0a(R2, R3, I2, I3, CT, ST, gi) {                             \
    const h2 _c = RLH(CT, 32 + (gi)), _s = RLH(ST, 32 + (gi));               \
    const h2 _ns = NEGH(_s);                                                 \
    const h2 _nr2 = FMH(_s, I3, _c * R2), _ni2 = FMH(_ns, R3, _c * I2);      \
    const h2 _nr3 = FMH(_s, I2, _c * R3), _ni3 = FMH(_ns, R2, _c * I3);      \
    R2 = _nr2; I2 = _ni2; R3 = _nr3; I3 = _ni3; }

    // gate 2: c=q2(b0: regs 1,3 always ctrl'd), t=q3(b7: lane^32)
#define CRX_I2(R1, R3, I1, I3, CT, ST) {                                     \
    const h2 _c = RLH(CT, 34), _s = RLH(ST, 34), _ns = NEGH(_s);             \
    const h2 _pr1 = BP32(R1), _pi1 = BP32(I1);                               \
    const h2 _pr3 = BP32(R3), _pi3 = BP32(I3);                               \
    R1 = FMH(_s, _pi1, _c * R1); I1 = FMH(_ns, _pr1, _c * I1);               \
    R3 = FMH(_s, _pi3, _c * R3); I3 = FMH(_ns, _pr3, _c * I3); }

    CRX_SLOT1_FIRST(rP0, rP1, rP2, rP3, iP0, iP1, iP2, iP3, cvP, svP)
    CRX_SLOT1_FIRST(rQ0, rQ1, rQ2, rQ3, iQ0, iQ1, iQ2, iQ3, cvQ, svQ)
    CRX_SLOT0a(rP2, rP3, iP2, iP3, cvP, svP, 1)
    CRX_SLOT0a(rQ2, rQ3, iQ2, iQ3, cvQ, svQ, 1)
    CRX_I2(rP1, rP3, iP1, iP3, cvP, svP)
    CRX_I2(rQ1, rQ3, iQ1, iQ3, cvQ, svQ)
    CRX_Ga(rP0, rP1, rP2, rP3, iP0, iP1, iP2, iP3, cvP, svP, 3, 32, BP16)
    CRX_Ga(rQ0, rQ1, rQ2, rQ3, iQ0, iQ1, iQ2, iQ3, cvQ, svQ, 3, 32, BP16)
    CRX_Ga(rP0, rP1, rP2, rP3, iP0, iP1, iP2, iP3, cvP, svP, 4, 16, PX8H)
    CRX_Ga(rQ0, rQ1, rQ2, rQ3, iQ0, iQ1, iQ2, iQ3, cvQ, svQ, 4, 16, PX8H)
    CRX_Ga(rP0, rP1, rP2, rP3, iP0, iP1, iP2, iP3, cvP, svP, 5, 8, PX4H)
    CRX_Ga(rQ0, rQ1, rQ2, rQ3, iQ0, iQ1, iQ2, iQ3, cvQ, svQ, 5, 8, PX4H)
    CRX_Ga(rP0, rP1, rP2, rP3, iP0, iP1, iP2, iP3, cvP, svP, 6, 4, PX2H)
    CRX_Ga(rQ0, rQ1, rQ2, rQ3, iQ0, iQ1, iQ2, iQ3, cvQ, svQ, 6, 4, PX2H)
    // gates 7,8,9: pruned (exact — do not affect <Z_q3>, <Z_q7>)

    // ---- probs (f16) -> f32 epilogue ----
    const h2 pP0 = FMH(rP0, rP0, iP0 * iP0);
    const h2 pP1 = FMH(rP1, rP1, iP1 * iP1);
    const h2 pP2 = FMH(rP2, rP2, iP2 * iP2);
    const h2 pP3 = FMH(rP3, rP3, iP3 * iP3);
    const h2 apP = (pP0 + pP1) + (pP2 + pP3);
    const h2 pQ0 = FMH(rQ0, rQ0, iQ0 * iQ0);
    const h2 pQ1 = FMH(rQ1, rQ1, iQ1 * iQ1);
    const h2 pQ2 = FMH(rQ2, rQ2, iQ2 * iQ2);
    const h2 pQ3 = FMH(rQ3, rQ3, iQ3 * iQ3);
    const h2 apQ = (pQ0 + pQ1) + (pQ2 + pQ3);
    float aAf = (float)apP.x, aBf = (float)apP.y;
    float aCf = (float)apQ.x, aDf = (float)apQ.y;

    // shared pre-reduction over lane bits {0,2,3,4} (sign-independent for
    // both z3 (bit5) and z7 (bit1)); then sign + finish over bits {5,1}.
#define RED4(v) { v += PX1S(v); v += PX4S(v); v += PX8S(v); v += BPFS(a16, v); }
    RED4(aAf) RED4(aBf) RED4(aCf) RED4(aDf)

#define ZPAIR(af, Z3, Z7)                                                    \
    float Z3 = (lane & 32) ? -(af) : (af);   /* q3 -> b7 (lane bit5) */      \
    Z3 += BPFS(a32, Z3); Z3 += PX2S(Z3);                                     \
    float Z7 = (lane & 2) ? -(af) : (af);    /* q7 -> b3 (lane bit1) */      \
    Z7 += PX2S(Z7); Z7 += BPFS(a32, Z7);

    ZPAIR(aAf, z3A, z7A)
    ZPAIR(aBf, z3B, z7B)
    ZPAIR(aCf, z3C, z7C)
    ZPAIR(aDf, z3D, z7D)

    // ---- MLP: lane u (<10) computes hidden unit u for all four states ----
    float wa = 0.f, wb = 0.f, bb = 0.f, wc = 0.f;
    if (lane < 10) {
        wa = w1[2 * lane];
        wb = w1[2 * lane + 1];
        bb = b1[lane];
        wc = w2[lane];
    }
    const float zA = fmaf(wa, z3A, fmaf(wb, z7A, bb));
    const float zB = fmaf(wa, z3B, fmaf(wb, z7B, bb));
    const float zC = fmaf(wa, z3C, fmaf(wb, z7C, bb));
    const float zD = fmaf(wa, z3D, fmaf(wb, z7D, bb));
    const float eA = __expf(2.0f * zA), eB = __expf(2.0f * zB);
    const float eC = __expf(2.0f * zC), eD = __expf(2.0f * zD);
    const float hA = 1.0f - 2.0f * __builtin_amdgcn_rcpf(eA + 1.0f);
    const float hB = 1.0f - 2.0f * __builtin_amdgcn_rcpf(eB + 1.0f);
    const float hC = 1.0f - 2.0f * __builtin_amdgcn_rcpf(eC + 1.0f);
    const float hD = 1.0f - 2.0f * __builtin_amdgcn_rcpf(eD + 1.0f);
    float accA = wc * hA, accB = wc * hB;    // lanes >=10 contribute 0
    float accC = wc * hC, accD = wc * hD;
    accA += PX1S(accA); accB += PX1S(accB); accC += PX1S(accC); accD += PX1S(accD);
    accA += PX2S(accA); accB += PX2S(accB); accC += PX2S(accC); accD += PX2S(accD);
    accA += PX4S(accA); accB += PX4S(accB); accC += PX4S(accC); accD += PX4S(accD);
    accA += PX8S(accA); accB += PX8S(accB); accC += PX8S(accC); accD += PX8S(accD);
    if (lane == 0) {
        const float bias = b2[0];
        float4 o;
        o.x = __builtin_amdgcn_rcpf(1.0f + __expf(-(accA + bias)));
        o.y = __builtin_amdgcn_rcpf(1.0f + __expf(-(accB + bias)));
        o.z = __builtin_amdgcn_rcpf(1.0f + __expf(-(accC + bias)));
        o.w = __builtin_amdgcn_rcpf(1.0f + __expf(-(accD + bias)));
        *reinterpret_cast<float4*>(out + b0) = o;
    }
}

extern "C" void kernel_launch(void* const* d_in, const int* in_sizes, int n_in,
                              void* d_out, int out_size, void* d_ws, size_t ws_size,
                              hipStream_t stream) {
    const float* x         = (const float*)d_in[0];
    const float* crx_theta = (const float*)d_in[1];
    const float* w1        = (const float*)d_in[2];
    const float* b1        = (const float*)d_in[3];
    const float* w2        = (const float*)d_in[4];
    const float* b2        = (const float*)d_in[5];
    float* out = (float*)d_out;

    const int B = in_sizes[0] / 32;  // x is (B, 4, 8)
    vqcnn_wave<<<B / 16, 256, 0, stream>>>(x, crx_theta, w1, b1, w2, b2, out);
}